// Round 2
// baseline (94.650 us; speedup 1.0000x reference)
//
#include <hip/hip_runtime.h>

#define B 4
#define L 512
#define H 768
#define S 100
#define R 100
#define E 25
#define NE 10
#define NR 6
#define NEGF (-1e20f)

// Block-wide mask stats for a contiguous 0/1 span: n = popcount, start = first
// set index. Wave shuffle reduce -> per-wave slot in LDS; caller combines the
// 4 wave slots after __syncthreads().
__device__ __forceinline__ void mask_stats_partial(
    const int* __restrict__ mrow, int t, int wave, int lane,
    int (*sc)[4], int (*sm)[4], int k)
{
    int c = 0, mn = L;
    #pragma unroll
    for (int i = 0; i < 2; ++i) {           // L=512 = 256 threads x 2
        const int l = t + i * 256;
        const int m = mrow[l];
        c += (m != 0);
        if (m != 0 && l < mn) mn = l;
    }
    for (int off = 32; off > 0; off >>= 1) {
        c += __shfl_down(c, off, 64);
        mn = min(mn, __shfl_down(mn, off, 64));
    }
    if (lane == 0) { sc[k][wave] = c; sm[k][wave] = mn; }
}

// Contiguous-span max-pool over hidden rows [start, start+n); each thread owns
// channels t, t+256, t+512 (coalesced across the wave, L2-hot rows).
__device__ __forceinline__ void span_pool(
    const float* __restrict__ hb, int start, int n,
    int h0, int h1, int h2, float& mv0, float& mv1, float& mv2)
{
    mv0 = NEGF; mv1 = NEGF; mv2 = NEGF;
    const float* hp = hb + (size_t)start * H;
    for (int i = 0; i < n; ++i, hp += H) {
        mv0 = fmaxf(mv0, hp[h0]);
        mv1 = fmaxf(mv1, hp[h1]);
        mv2 = fmaxf(mv2, hp[h2]);
    }
}

// One fused kernel: blocks j<S do entity pooling + entity logits; blocks j>=S
// do relation context pooling + head/tail entity re-pooling + relation logits.
// grid = B*(S+R), block = 256 (4 waves). No workspace, no inter-kernel dep.
__global__ __launch_bounds__(256) void spert_fused_kernel(
    const float* __restrict__ hidden,     // (B, L, H)
    const int*   __restrict__ emask,      // (B, S, L)
    const int*   __restrict__ relations,  // (B, R, 2)
    const int*   __restrict__ cmask,      // (B, R, L)
    const float* __restrict__ size_emb,   // (MAXLEN, E)
    const float* __restrict__ w_span,     // (H+E, NE)
    const float* __restrict__ b_span,     // (NE,)
    const float* __restrict__ w_rel,      // (3H+2E, NR)
    const float* __restrict__ b_rel,      // (NR,)
    float* __restrict__ ent_logits,       // out: (B, S, NE)
    float* __restrict__ rel_logits)       // out: (B, R, NR)
{
    const int idx  = blockIdx.x;
    const int b    = idx / (S + R);
    const int j    = idx % (S + R);
    const int t    = threadIdx.x;
    const int wave = t >> 6;
    const int lane = t & 63;
    const int h0 = t, h1 = t + 256, h2 = t + 512;

    __shared__ int   sc[3][4], sm[3][4];
    __shared__ float sred[4][NE];

    const float* hb = hidden + (size_t)b * L * H;

    if (j < S) {
        // ---------------- entity span block ----------------
        const int* mrow = emask + (size_t)(b * S + j) * L;
        mask_stats_partial(mrow, t, wave, lane, sc, sm, 0);
        __syncthreads();
        const int n     = sc[0][0] + sc[0][1] + sc[0][2] + sc[0][3];
        const int start = min(min(sm[0][0], sm[0][1]), min(sm[0][2], sm[0][3]));

        float mv0, mv1, mv2;
        span_pool(hb, start, n, h0, h1, h2, mv0, mv1, mv2);

        // partial logits: hidden part via owned channels, size part via t<E
        float p[NE];
        #pragma unroll
        for (int o = 0; o < NE; ++o)
            p[o] = mv0 * w_span[(size_t)h0 * NE + o]
                 + mv1 * w_span[(size_t)h1 * NE + o]
                 + mv2 * w_span[(size_t)h2 * NE + o];
        if (t < E) {
            const float sz = size_emb[(size_t)n * E + t];
            #pragma unroll
            for (int o = 0; o < NE; ++o) p[o] += sz * w_span[(size_t)(H + t) * NE + o];
        }
        #pragma unroll
        for (int o = 0; o < NE; ++o) {
            float v = p[o];
            for (int off = 32; off > 0; off >>= 1) v += __shfl_down(v, off, 64);
            p[o] = v;
        }
        if (lane == 0) {
            #pragma unroll
            for (int o = 0; o < NE; ++o) sred[wave][o] = p[o];
        }
        __syncthreads();
        if (t < NE) {
            const float v = sred[0][t] + sred[1][t] + sred[2][t] + sred[3][t] + b_span[t];
            ent_logits[(size_t)(b * S + j) * NE + t] = v;
        }
    } else {
        // ---------------- relation block ----------------
        const int r    = j - S;
        const int head = relations[(size_t)(b * R + r) * 2 + 0];
        const int tail = relations[(size_t)(b * R + r) * 2 + 1];

        mask_stats_partial(cmask + (size_t)(b * R + r)    * L, t, wave, lane, sc, sm, 0);
        mask_stats_partial(emask + (size_t)(b * S + head) * L, t, wave, lane, sc, sm, 1);
        mask_stats_partial(emask + (size_t)(b * S + tail) * L, t, wave, lane, sc, sm, 2);
        __syncthreads();

        int n[3], st[3];
        #pragma unroll
        for (int k = 0; k < 3; ++k) {
            n[k]  = sc[k][0] + sc[k][1] + sc[k][2] + sc[k][3];
            st[k] = min(min(sm[k][0], sm[k][1]), min(sm[k][2], sm[k][3]));
        }

        float mv[3][3];
        #pragma unroll
        for (int k = 0; k < 3; ++k)
            span_pool(hb, st[k], n[k], h0, h1, h2, mv[k][0], mv[k][1], mv[k][2]);

        // rel_repr feature rows: ctx->h, e_head->H+h, e_tail->2H+h,
        //                        sz_head->3H+e, sz_tail->3H+E+e
        float p[NR];
        #pragma unroll
        for (int o = 0; o < NR; ++o)
            p[o] = mv[0][0] * w_rel[(size_t) h0          * NR + o]
                 + mv[0][1] * w_rel[(size_t) h1          * NR + o]
                 + mv[0][2] * w_rel[(size_t) h2          * NR + o]
                 + mv[1][0] * w_rel[(size_t)(H + h0)     * NR + o]
                 + mv[1][1] * w_rel[(size_t)(H + h1)     * NR + o]
                 + mv[1][2] * w_rel[(size_t)(H + h2)     * NR + o]
                 + mv[2][0] * w_rel[(size_t)(2 * H + h0) * NR + o]
                 + mv[2][1] * w_rel[(size_t)(2 * H + h1) * NR + o]
                 + mv[2][2] * w_rel[(size_t)(2 * H + h2) * NR + o];
        if (t < E) {
            const float sz = size_emb[(size_t)n[1] * E + t];
            #pragma unroll
            for (int o = 0; o < NR; ++o) p[o] += sz * w_rel[(size_t)(3 * H + t) * NR + o];
        } else if (t >= 32 && t < 32 + E) {
            const int e = t - 32;
            const float sz = size_emb[(size_t)n[2] * E + e];
            #pragma unroll
            for (int o = 0; o < NR; ++o) p[o] += sz * w_rel[(size_t)(3 * H + E + e) * NR + o];
        }

        #pragma unroll
        for (int o = 0; o < NR; ++o) {
            float v = p[o];
            for (int off = 32; off > 0; off >>= 1) v += __shfl_down(v, off, 64);
            p[o] = v;
        }
        if (lane == 0) {
            #pragma unroll
            for (int o = 0; o < NR; ++o) sred[wave][o] = p[o];
        }
        __syncthreads();
        if (t < NR) {
            const float v = sred[0][t] + sred[1][t] + sred[2][t] + sred[3][t] + b_rel[t];
            rel_logits[(size_t)(b * R + r) * NR + t] = v;
        }
    }
}

extern "C" void kernel_launch(void* const* d_in, const int* in_sizes, int n_in,
                              void* d_out, int out_size, void* d_ws, size_t ws_size,
                              hipStream_t stream) {
    const float* hidden    = (const float*)d_in[0];
    const int*   emask     = (const int*)  d_in[1];
    const int*   relations = (const int*)  d_in[2];
    const int*   cmask     = (const int*)  d_in[3];
    const float* size_emb  = (const float*)d_in[4];
    const float* w_span    = (const float*)d_in[5];
    const float* b_span    = (const float*)d_in[6];
    const float* w_rel     = (const float*)d_in[7];
    const float* b_rel     = (const float*)d_in[8];

    float* out        = (float*)d_out;
    float* ent_logits = out;                 // (B, S, NE) = 4000 floats
    float* rel_logits = out + B * S * NE;    // (B, R, NR) = 2400 floats

    spert_fused_kernel<<<B * (S + R), 256, 0, stream>>>(
        hidden, emask, relations, cmask, size_emb,
        w_span, b_span, w_rel, b_rel, ent_logits, rel_logits);
}

// Round 3
// 93.200 us; speedup vs baseline: 1.0156x; 1.0156x over previous
//
#include <hip/hip_runtime.h>

#define B 4
#define L 512
#define H 768
#define S 100
#define R 100
#define E 25
#define NE 10
#define NR 6
#define NEGF (-1e20f)
#define TPB 192   // 3 waves; each thread owns one float4 of the H=768 channels

// Contiguous 0/1 span stats: n = popcount, start = first set index.
// Wave shuffle reduce -> 3 LDS slots -> block combine. One __syncthreads.
__device__ __forceinline__ void mask_stats(const int* __restrict__ mrow,
                                           int t, int wave, int lane,
                                           int* sc, int* sm, int& n, int& start)
{
    int c = 0, mn = L;
    for (int l = t; l < L; l += TPB) {
        const int m = mrow[l];
        c += (m != 0);
        if (m != 0 && l < mn) mn = l;
    }
    for (int off = 32; off > 0; off >>= 1) {
        c += __shfl_down(c, off, 64);
        mn = min(mn, __shfl_down(mn, off, 64));
    }
    if (lane == 0) { sc[wave] = c; sm[wave] = mn; }
    __syncthreads();
    n = sc[0] + sc[1] + sc[2];
    start = min(min(sm[0], sm[1]), sm[2]);
}

// Max-pool rows [start, start+n): one float4 per thread, coalesced 16B/lane.
__device__ __forceinline__ float4 span_pool4(const float* __restrict__ hb,
                                             int start, int n, int t)
{
    float4 mv = make_float4(NEGF, NEGF, NEGF, NEGF);
    const float4* hp = reinterpret_cast<const float4*>(hb + (size_t)start * H) + t;
    for (int i = 0; i < n; ++i, hp += H / 4) {
        const float4 v = *hp;
        mv.x = fmaxf(mv.x, v.x); mv.y = fmaxf(mv.y, v.y);
        mv.z = fmaxf(mv.z, v.z); mv.w = fmaxf(mv.w, v.w);
    }
    return mv;
}

template <int NO>
__device__ __forceinline__ void block_reduce_store(float* p, int t, int wave, int lane,
                                                   float (*sred)[NO],
                                                   const float* __restrict__ bias,
                                                   float* __restrict__ outrow)
{
    #pragma unroll
    for (int o = 0; o < NO; ++o) {
        float v = p[o];
        for (int off = 32; off > 0; off >>= 1) v += __shfl_down(v, off, 64);
        p[o] = v;
    }
    if (lane == 0) {
        #pragma unroll
        for (int o = 0; o < NO; ++o) sred[wave][o] = p[o];
    }
    __syncthreads();
    if (t < NO) outrow[t] = sred[0][t] + sred[1][t] + sred[2][t] + bias[t];
}

// ---------------------------------------------------------------------------
// K1: entity-span blocks (j<S): pool + fused entity logits + write entity row.
//     context blocks (j>=S): pool + write ctx row.
// grid = B*(S+R), block = 192
// ---------------------------------------------------------------------------
__global__ __launch_bounds__(TPB) void pool_kernel(
    const float* __restrict__ hidden,     // (B, L, H)
    const int*   __restrict__ emask,      // (B, S, L)
    const int*   __restrict__ cmask,      // (B, R, L)
    const float* __restrict__ size_emb,   // (MAXLEN, E)
    const float* __restrict__ w_span,     // (H+E, NE)
    const float* __restrict__ b_span,     // (NE,)
    float* __restrict__ entities,         // ws: (B, S, H)
    int*   __restrict__ n_ent,            // ws: (B, S)
    float* __restrict__ rel_ctx,          // ws: (B, R, H)
    float* __restrict__ ent_logits)       // out: (B, S, NE)
{
    const int idx  = blockIdx.x;
    const int b    = idx / (S + R);
    const int j    = idx % (S + R);
    const int t    = threadIdx.x;
    const int wave = t >> 6;
    const int lane = t & 63;

    __shared__ int   sc[3], sm[3];
    __shared__ float sred[3][NE];

    const float* hb = hidden + (size_t)b * L * H;
    const int* mrow = (j < S) ? (emask + (size_t)(b * S + j) * L)
                              : (cmask + (size_t)(b * R + (j - S)) * L);
    int n, start;
    mask_stats(mrow, t, wave, lane, sc, sm, n, start);

    const float4 mv = span_pool4(hb, start, n, t);

    if (j >= S) {
        reinterpret_cast<float4*>(rel_ctx + (size_t)(b * R + (j - S)) * H)[t] = mv;
        return;
    }

    reinterpret_cast<float4*>(entities + (size_t)(b * S + j) * H)[t] = mv;
    if (t == 0) n_ent[b * S + j] = n;

    // fused entity logits: 4 contiguous w_span rows per thread
    float p[NE];
    const float* w0 = w_span + (size_t)(4 * t) * NE;
    #pragma unroll
    for (int o = 0; o < NE; ++o)
        p[o] = mv.x * w0[o] + mv.y * w0[NE + o] + mv.z * w0[2 * NE + o] + mv.w * w0[3 * NE + o];
    if (t < E) {
        const float sz = size_emb[(size_t)n * E + t];
        #pragma unroll
        for (int o = 0; o < NE; ++o) p[o] += sz * w_span[(size_t)(H + t) * NE + o];
    }
    block_reduce_store<NE>(p, t, wave, lane, sred, b_span,
                           ent_logits + (size_t)(b * S + j) * NE);
}

// ---------------------------------------------------------------------------
// K2: relation logits from pooled rows. grid = B*R, block = 192
// rel_repr rows: ctx->i, e_head->H+i, e_tail->2H+i, sz_head->3H+e, sz_tail->3H+E+e
// ---------------------------------------------------------------------------
__global__ __launch_bounds__(TPB) void rel_kernel(
    const float* __restrict__ entities,   // ws: (B, S, H)
    const int*   __restrict__ n_ent,      // ws: (B, S)
    const float* __restrict__ rel_ctx,    // ws: (B, R, H)
    const int*   __restrict__ relations,  // (B, R, 2)
    const float* __restrict__ size_emb,   // (MAXLEN, E)
    const float* __restrict__ w_rel,      // (3H+2E, NR)
    const float* __restrict__ b_rel,      // (NR,)
    float* __restrict__ rel_logits)       // out: (B, R, NR)
{
    const int idx  = blockIdx.x;
    const int b    = idx / R;
    const int r    = idx % R;
    const int t    = threadIdx.x;
    const int wave = t >> 6;
    const int lane = t & 63;

    const int head = relations[(size_t)(b * R + r) * 2 + 0];
    const int tail = relations[(size_t)(b * R + r) * 2 + 1];

    const float4 c4 = reinterpret_cast<const float4*>(rel_ctx  + (size_t)(b * R + r)    * H)[t];
    const float4 h4 = reinterpret_cast<const float4*>(entities + (size_t)(b * S + head) * H)[t];
    const float4 t4 = reinterpret_cast<const float4*>(entities + (size_t)(b * S + tail) * H)[t];

    float p[NR];
    const float* wc = w_rel + (size_t)(4 * t) * NR;
    const float* wh = w_rel + (size_t)(H + 4 * t) * NR;
    const float* wt = w_rel + (size_t)(2 * H + 4 * t) * NR;
    #pragma unroll
    for (int o = 0; o < NR; ++o)
        p[o] = c4.x * wc[o] + c4.y * wc[NR + o] + c4.z * wc[2 * NR + o] + c4.w * wc[3 * NR + o]
             + h4.x * wh[o] + h4.y * wh[NR + o] + h4.z * wh[2 * NR + o] + h4.w * wh[3 * NR + o]
             + t4.x * wt[o] + t4.y * wt[NR + o] + t4.z * wt[2 * NR + o] + t4.w * wt[3 * NR + o];

    if (t < E) {                       // wave 0: head size part
        const float sz = size_emb[(size_t)n_ent[b * S + head] * E + t];
        #pragma unroll
        for (int o = 0; o < NR; ++o) p[o] += sz * w_rel[(size_t)(3 * H + t) * NR + o];
    } else if (t >= 64 && t < 64 + E) { // wave 1: tail size part
        const int e = t - 64;
        const float sz = size_emb[(size_t)n_ent[b * S + tail] * E + e];
        #pragma unroll
        for (int o = 0; o < NR; ++o) p[o] += sz * w_rel[(size_t)(3 * H + E + e) * NR + o];
    }

    __shared__ float sred[3][NR];
    block_reduce_store<NR>(p, t, wave, lane, sred, b_rel,
                           rel_logits + (size_t)(b * R + r) * NR);
}

extern "C" void kernel_launch(void* const* d_in, const int* in_sizes, int n_in,
                              void* d_out, int out_size, void* d_ws, size_t ws_size,
                              hipStream_t stream) {
    const float* hidden    = (const float*)d_in[0];
    const int*   emask     = (const int*)  d_in[1];
    const int*   relations = (const int*)  d_in[2];
    const int*   cmask     = (const int*)  d_in[3];
    const float* size_emb  = (const float*)d_in[4];
    const float* w_span    = (const float*)d_in[5];
    const float* b_span    = (const float*)d_in[6];
    const float* w_rel     = (const float*)d_in[7];
    const float* b_rel     = (const float*)d_in[8];

    float* out        = (float*)d_out;
    float* ent_logits = out;                 // (B, S, NE) = 4000 floats
    float* rel_logits = out + B * S * NE;    // (B, R, NR) = 2400 floats

    float* ws       = (float*)d_ws;
    float* entities = ws;                              // B*S*H floats
    float* rel_ctx  = entities + (size_t)B * S * H;    // B*R*H floats
    int*   n_ent    = (int*)(rel_ctx + (size_t)B * R * H); // B*S ints

    pool_kernel<<<B * (S + R), TPB, 0, stream>>>(
        hidden, emask, cmask, size_emb, w_span, b_span,
        entities, n_ent, rel_ctx, ent_logits);

    rel_kernel<<<B * R, TPB, 0, stream>>>(
        entities, n_ent, rel_ctx, relations, size_emb, w_rel, b_rel, rel_logits);
}

// Round 4
// 85.355 us; speedup vs baseline: 1.1089x; 1.0919x over previous
//
#include <hip/hip_runtime.h>

#define B 4
#define L 512
#define H 768
#define S 100
#define R 100
#define E 25
#define NE 10
#define NR 6
#define NEGF (-1e20f)
#define TPB 192   // 3 waves; each thread owns one float4 of the H=768 channels

__device__ __forceinline__ float4 fmax4(float4 a, float4 b) {
    return make_float4(fmaxf(a.x, b.x), fmaxf(a.y, b.y),
                       fmaxf(a.z, b.z), fmaxf(a.w, b.w));
}

// Contiguous 0/1 span stats: n = popcount, start = first set index.
// int4 mask read (threads 0..127 cover L=512), wave shuffle reduce, LDS combine.
__device__ __forceinline__ void mask_stats(const int* __restrict__ mrow,
                                           int t, int wave, int lane,
                                           int* sc, int* sm, int& n, int& start)
{
    int c = 0, mn = L;
    if (t < L / 4) {
        const int4 m = reinterpret_cast<const int4*>(mrow)[t];
        c = (m.x != 0) + (m.y != 0) + (m.z != 0) + (m.w != 0);
        if (m.w != 0) mn = 4 * t + 3;
        if (m.z != 0) mn = 4 * t + 2;
        if (m.y != 0) mn = 4 * t + 1;
        if (m.x != 0) mn = 4 * t;
    }
    for (int off = 32; off > 0; off >>= 1) {
        c += __shfl_down(c, off, 64);
        mn = min(mn, __shfl_down(mn, off, 64));
    }
    if (lane == 0) { sc[wave] = c; sm[wave] = mn; }
    __syncthreads();
    n = sc[0] + sc[1] + sc[2];
    start = min(min(sm[0], sm[1]), sm[2]);
}

// Max-pool rows [start, start+n): 4-way row unroll -> 4 independent float4
// loads in flight per iteration (breaks the per-row L2-latency serial chain).
__device__ __forceinline__ float4 span_pool4(const float* __restrict__ hb,
                                             int start, int n, int t)
{
    const int st = H / 4;  // row stride in float4
    const float4* hp = reinterpret_cast<const float4*>(hb) + (size_t)start * st + t;
    float4 a0 = make_float4(NEGF, NEGF, NEGF, NEGF);
    float4 a1 = a0, a2 = a0, a3 = a0;
    int i = 0;
    for (; i + 4 <= n; i += 4) {
        const float4 v0 = hp[0 * st];
        const float4 v1 = hp[1 * st];
        const float4 v2 = hp[2 * st];
        const float4 v3 = hp[3 * st];
        a0 = fmax4(a0, v0); a1 = fmax4(a1, v1);
        a2 = fmax4(a2, v2); a3 = fmax4(a3, v3);
        hp += 4 * st;
    }
    for (; i < n; ++i) { a0 = fmax4(a0, hp[0]); hp += st; }
    return fmax4(fmax4(a0, a1), fmax4(a2, a3));
}

template <int NO>
__device__ __forceinline__ void block_reduce_store(float* p, int t, int wave, int lane,
                                                   float (*sred)[NO],
                                                   const float* __restrict__ bias,
                                                   float* __restrict__ outrow)
{
    #pragma unroll
    for (int o = 0; o < NO; ++o) {
        float v = p[o];
        for (int off = 32; off > 0; off >>= 1) v += __shfl_down(v, off, 64);
        p[o] = v;
    }
    if (lane == 0) {
        #pragma unroll
        for (int o = 0; o < NO; ++o) sred[wave][o] = p[o];
    }
    __syncthreads();
    if (t < NO) outrow[t] = sred[0][t] + sred[1][t] + sred[2][t] + bias[t];
}

// ---------------------------------------------------------------------------
// K1: entity-span blocks (j<S): pool + fused entity logits + write entity row.
//     context blocks (j>=S): pool + write ctx row.  grid = B*(S+R), block = 192
// ---------------------------------------------------------------------------
__global__ __launch_bounds__(TPB) void pool_kernel(
    const float* __restrict__ hidden,     // (B, L, H)
    const int*   __restrict__ emask,      // (B, S, L)
    const int*   __restrict__ cmask,      // (B, R, L)
    const float* __restrict__ size_emb,   // (MAXLEN, E)
    const float* __restrict__ w_span,     // (H+E, NE)
    const float* __restrict__ b_span,     // (NE,)
    float* __restrict__ entities,         // ws: (B, S, H)
    int*   __restrict__ n_ent,            // ws: (B, S)
    float* __restrict__ rel_ctx,          // ws: (B, R, H)
    float* __restrict__ ent_logits)       // out: (B, S, NE)
{
    const int idx  = blockIdx.x;
    const int b    = idx / (S + R);
    const int j    = idx % (S + R);
    const int t    = threadIdx.x;
    const int wave = t >> 6;
    const int lane = t & 63;

    __shared__ int   sc[3], sm[3];
    __shared__ float sred[3][NE];

    const float* hb = hidden + (size_t)b * L * H;
    const int* mrow = (j < S) ? (emask + (size_t)(b * S + j) * L)
                              : (cmask + (size_t)(b * R + (j - S)) * L);
    int n, start;
    mask_stats(mrow, t, wave, lane, sc, sm, n, start);

    const float4 mv = span_pool4(hb, start, n, t);

    if (j >= S) {
        reinterpret_cast<float4*>(rel_ctx + (size_t)(b * R + (j - S)) * H)[t] = mv;
        return;
    }

    reinterpret_cast<float4*>(entities + (size_t)(b * S + j) * H)[t] = mv;
    if (t == 0) n_ent[b * S + j] = n;

    // fused entity logits: 4 contiguous w_span rows per thread
    float p[NE];
    const float* w0 = w_span + (size_t)(4 * t) * NE;
    #pragma unroll
    for (int o = 0; o < NE; ++o)
        p[o] = mv.x * w0[o] + mv.y * w0[NE + o] + mv.z * w0[2 * NE + o] + mv.w * w0[3 * NE + o];
    if (t < E) {
        const float sz = size_emb[(size_t)n * E + t];
        #pragma unroll
        for (int o = 0; o < NE; ++o) p[o] += sz * w_span[(size_t)(H + t) * NE + o];
    }
    block_reduce_store<NE>(p, t, wave, lane, sred, b_span,
                           ent_logits + (size_t)(b * S + j) * NE);
}

// ---------------------------------------------------------------------------
// K2: relation logits from pooled rows. grid = B*R, block = 192
// rel_repr rows: ctx->i, e_head->H+i, e_tail->2H+i, sz_head->3H+e, sz_tail->3H+E+e
// ---------------------------------------------------------------------------
__global__ __launch_bounds__(TPB) void rel_kernel(
    const float* __restrict__ entities,   // ws: (B, S, H)
    const int*   __restrict__ n_ent,      // ws: (B, S)
    const float* __restrict__ rel_ctx,    // ws: (B, R, H)
    const int*   __restrict__ relations,  // (B, R, 2)
    const float* __restrict__ size_emb,   // (MAXLEN, E)
    const float* __restrict__ w_rel,      // (3H+2E, NR)
    const float* __restrict__ b_rel,      // (NR,)
    float* __restrict__ rel_logits)       // out: (B, R, NR)
{
    const int idx  = blockIdx.x;
    const int b    = idx / R;
    const int r    = idx % R;
    const int t    = threadIdx.x;
    const int wave = t >> 6;
    const int lane = t & 63;

    const int head = relations[(size_t)(b * R + r) * 2 + 0];
    const int tail = relations[(size_t)(b * R + r) * 2 + 1];

    const float4 c4 = reinterpret_cast<const float4*>(rel_ctx  + (size_t)(b * R + r)    * H)[t];
    const float4 h4 = reinterpret_cast<const float4*>(entities + (size_t)(b * S + head) * H)[t];
    const float4 t4 = reinterpret_cast<const float4*>(entities + (size_t)(b * S + tail) * H)[t];

    float p[NR];
    const float* wc = w_rel + (size_t)(4 * t) * NR;
    const float* wh = w_rel + (size_t)(H + 4 * t) * NR;
    const float* wt = w_rel + (size_t)(2 * H + 4 * t) * NR;
    #pragma unroll
    for (int o = 0; o < NR; ++o)
        p[o] = c4.x * wc[o] + c4.y * wc[NR + o] + c4.z * wc[2 * NR + o] + c4.w * wc[3 * NR + o]
             + h4.x * wh[o] + h4.y * wh[NR + o] + h4.z * wh[2 * NR + o] + h4.w * wh[3 * NR + o]
             + t4.x * wt[o] + t4.y * wt[NR + o] + t4.z * wt[2 * NR + o] + t4.w * wt[3 * NR + o];

    if (t < E) {                        // wave 0: head size part
        const float sz = size_emb[(size_t)n_ent[b * S + head] * E + t];
        #pragma unroll
        for (int o = 0; o < NR; ++o) p[o] += sz * w_rel[(size_t)(3 * H + t) * NR + o];
    } else if (t >= 64 && t < 64 + E) { // wave 1: tail size part
        const int e = t - 64;
        const float sz = size_emb[(size_t)n_ent[b * S + tail] * E + e];
        #pragma unroll
        for (int o = 0; o < NR; ++o) p[o] += sz * w_rel[(size_t)(3 * H + E + e) * NR + o];
    }

    __shared__ float sred[3][NR];
    block_reduce_store<NR>(p, t, wave, lane, sred, b_rel,
                           rel_logits + (size_t)(b * R + r) * NR);
}

extern "C" void kernel_launch(void* const* d_in, const int* in_sizes, int n_in,
                              void* d_out, int out_size, void* d_ws, size_t ws_size,
                              hipStream_t stream) {
    const float* hidden    = (const float*)d_in[0];
    const int*   emask     = (const int*)  d_in[1];
    const int*   relations = (const int*)  d_in[2];
    const int*   cmask     = (const int*)  d_in[3];
    const float* size_emb  = (const float*)d_in[4];
    const float* w_span    = (const float*)d_in[5];
    const float* b_span    = (const float*)d_in[6];
    const float* w_rel     = (const float*)d_in[7];
    const float* b_rel     = (const float*)d_in[8];

    float* out        = (float*)d_out;
    float* ent_logits = out;                 // (B, S, NE) = 4000 floats
    float* rel_logits = out + B * S * NE;    // (B, R, NR) = 2400 floats

    float* ws       = (float*)d_ws;
    float* entities = ws;                                  // B*S*H floats
    float* rel_ctx  = entities + (size_t)B * S * H;        // B*R*H floats
    int*   n_ent    = (int*)(rel_ctx + (size_t)B * R * H); // B*S ints

    pool_kernel<<<B * (S + R), TPB, 0, stream>>>(
        hidden, emask, cmask, size_emb, w_span, b_span,
        entities, n_ent, rel_ctx, ent_logits);

    rel_kernel<<<B * R, TPB, 0, stream>>>(
        entities, n_ent, rel_ctx, relations, size_emb, w_rel, b_rel, rel_logits);
}

// Round 5
// 85.105 us; speedup vs baseline: 1.1122x; 1.0029x over previous
//
#include <hip/hip_runtime.h>

#define B 4
#define L 512
#define H 768
#define S 100
#define R 100
#define E 25
#define NE 10
#define NR 6
#define NEGF (-1e20f)
#define TPB 192   // 3 waves; each thread owns one float4 of the H=768 channels

__device__ __forceinline__ float4 fmax4(float4 a, float4 b) {
    return make_float4(fmaxf(a.x, b.x), fmaxf(a.y, b.y),
                       fmaxf(a.z, b.z), fmaxf(a.w, b.w));
}

// Contiguous 0/1 span stats: n = popcount, start = first set index.
// Threads 0..127 read one int4 each (covers L=512). Per-wave ballots over the
// 4 components -> popcount/ctz in scalar regs; no shuffle chain.
// Wave w covers l in [256w, 256w+256): lane i <-> l = 4*(64w+i)+comp.
__device__ __forceinline__ void mask_stats(const int* __restrict__ mrow,
                                           int t, int wave, int lane,
                                           int* sc, int* sm, int& n, int& start)
{
    int4 m = make_int4(0, 0, 0, 0);
    if (t < L / 4) m = reinterpret_cast<const int4*>(mrow)[t];
    const unsigned long long b0 = __ballot(m.x != 0);
    const unsigned long long b1 = __ballot(m.y != 0);
    const unsigned long long b2 = __ballot(m.z != 0);
    const unsigned long long b3 = __ballot(m.w != 0);
    if (lane == 0 && wave < 2) {
        const int c = __popcll(b0) + __popcll(b1) + __popcll(b2) + __popcll(b3);
        int mn = L;
        if (b3) mn = min(mn, 4 * __builtin_ctzll(b3) + 3);
        if (b2) mn = min(mn, 4 * __builtin_ctzll(b2) + 2);
        if (b1) mn = min(mn, 4 * __builtin_ctzll(b1) + 1);
        if (b0) mn = min(mn, 4 * __builtin_ctzll(b0));
        sc[wave] = c;
        sm[wave] = (mn < L) ? (256 * wave + mn) : L;
    }
    __syncthreads();
    n = sc[0] + sc[1];
    start = min(sm[0], sm[1]);
}

// Max-pool rows [start, start+n): 8-way row unroll, row index clamped to
// n-1 (idempotent for max; start+n+7 <= 469 < L so reads stay in-bounds).
// 8 independent float4 loads in flight -> ~ceil(n/8) latency slots.
__device__ __forceinline__ float4 span_pool4(const float* __restrict__ hb,
                                             int start, int n, int t)
{
    const int st = H / 4;  // row stride in float4
    const float4* base = reinterpret_cast<const float4*>(hb) + (size_t)start * st + t;
    float4 a0 = make_float4(NEGF, NEGF, NEGF, NEGF);
    float4 a1 = a0, a2 = a0, a3 = a0, a4 = a0, a5 = a0, a6 = a0, a7 = a0;
    const int last = n - 1;
    for (int i = 0; i < n; i += 8) {
        const float4 v0 = base[(size_t)min(i + 0, last) * st];
        const float4 v1 = base[(size_t)min(i + 1, last) * st];
        const float4 v2 = base[(size_t)min(i + 2, last) * st];
        const float4 v3 = base[(size_t)min(i + 3, last) * st];
        const float4 v4 = base[(size_t)min(i + 4, last) * st];
        const float4 v5 = base[(size_t)min(i + 5, last) * st];
        const float4 v6 = base[(size_t)min(i + 6, last) * st];
        const float4 v7 = base[(size_t)min(i + 7, last) * st];
        a0 = fmax4(a0, v0); a1 = fmax4(a1, v1);
        a2 = fmax4(a2, v2); a3 = fmax4(a3, v3);
        a4 = fmax4(a4, v4); a5 = fmax4(a5, v5);
        a6 = fmax4(a6, v6); a7 = fmax4(a7, v7);
    }
    return fmax4(fmax4(fmax4(a0, a1), fmax4(a2, a3)),
                 fmax4(fmax4(a4, a5), fmax4(a6, a7)));
}

template <int NO>
__device__ __forceinline__ void block_reduce_store(float* p, int t, int wave, int lane,
                                                   float (*sred)[NO],
                                                   const float* __restrict__ bias,
                                                   float* __restrict__ outrow)
{
    #pragma unroll
    for (int o = 0; o < NO; ++o) {
        float v = p[o];
        for (int off = 32; off > 0; off >>= 1) v += __shfl_down(v, off, 64);
        p[o] = v;
    }
    if (lane == 0) {
        #pragma unroll
        for (int o = 0; o < NO; ++o) sred[wave][o] = p[o];
    }
    __syncthreads();
    if (t < NO) outrow[t] = sred[0][t] + sred[1][t] + sred[2][t] + bias[t];
}

// ---------------------------------------------------------------------------
// K1: entity-span blocks (j<S): pool + fused entity logits + write entity row.
//     context blocks (j>=S): pool + write ctx row.  grid = B*(S+R), block = 192
// ---------------------------------------------------------------------------
__global__ __launch_bounds__(TPB) void pool_kernel(
    const float* __restrict__ hidden,     // (B, L, H)
    const int*   __restrict__ emask,      // (B, S, L)
    const int*   __restrict__ cmask,      // (B, R, L)
    const float* __restrict__ size_emb,   // (MAXLEN, E)
    const float* __restrict__ w_span,     // (H+E, NE)
    const float* __restrict__ b_span,     // (NE,)
    float* __restrict__ entities,         // ws: (B, S, H)
    int*   __restrict__ n_ent,            // ws: (B, S)
    float* __restrict__ rel_ctx,          // ws: (B, R, H)
    float* __restrict__ ent_logits)       // out: (B, S, NE)
{
    const int idx  = blockIdx.x;
    const int b    = idx / (S + R);
    const int j    = idx % (S + R);
    const int t    = threadIdx.x;
    const int wave = t >> 6;
    const int lane = t & 63;

    __shared__ int   sc[2], sm[2];
    __shared__ float sred[3][NE];

    const float* hb = hidden + (size_t)b * L * H;
    const int* mrow = (j < S) ? (emask + (size_t)(b * S + j) * L)
                              : (cmask + (size_t)(b * R + (j - S)) * L);
    int n, start;
    mask_stats(mrow, t, wave, lane, sc, sm, n, start);

    const float4 mv = span_pool4(hb, start, n, t);

    if (j >= S) {
        reinterpret_cast<float4*>(rel_ctx + (size_t)(b * R + (j - S)) * H)[t] = mv;
        return;
    }

    reinterpret_cast<float4*>(entities + (size_t)(b * S + j) * H)[t] = mv;
    if (t == 0) n_ent[b * S + j] = n;

    // fused entity logits: 4 contiguous w_span rows per thread
    float p[NE];
    const float* w0 = w_span + (size_t)(4 * t) * NE;
    #pragma unroll
    for (int o = 0; o < NE; ++o)
        p[o] = mv.x * w0[o] + mv.y * w0[NE + o] + mv.z * w0[2 * NE + o] + mv.w * w0[3 * NE + o];
    if (t < E) {
        const float sz = size_emb[(size_t)n * E + t];
        #pragma unroll
        for (int o = 0; o < NE; ++o) p[o] += sz * w_span[(size_t)(H + t) * NE + o];
    }
    block_reduce_store<NE>(p, t, wave, lane, sred, b_span,
                           ent_logits + (size_t)(b * S + j) * NE);
}

// ---------------------------------------------------------------------------
// K2: relation logits from pooled rows. grid = B*R, block = 192
// rel_repr rows: ctx->i, e_head->H+i, e_tail->2H+i, sz_head->3H+e, sz_tail->3H+E+e
// ---------------------------------------------------------------------------
__global__ __launch_bounds__(TPB) void rel_kernel(
    const float* __restrict__ entities,   // ws: (B, S, H)
    const int*   __restrict__ n_ent,      // ws: (B, S)
    const float* __restrict__ rel_ctx,    // ws: (B, R, H)
    const int*   __restrict__ relations,  // (B, R, 2)
    const float* __restrict__ size_emb,   // (MAXLEN, E)
    const float* __restrict__ w_rel,      // (3H+2E, NR)
    const float* __restrict__ b_rel,      // (NR,)
    float* __restrict__ rel_logits)       // out: (B, R, NR)
{
    const int idx  = blockIdx.x;
    const int b    = idx / R;
    const int r    = idx % R;
    const int t    = threadIdx.x;
    const int wave = t >> 6;
    const int lane = t & 63;

    const int head = relations[(size_t)(b * R + r) * 2 + 0];
    const int tail = relations[(size_t)(b * R + r) * 2 + 1];

    const float4 c4 = reinterpret_cast<const float4*>(rel_ctx  + (size_t)(b * R + r)    * H)[t];
    const float4 h4 = reinterpret_cast<const float4*>(entities + (size_t)(b * S + head) * H)[t];
    const float4 t4 = reinterpret_cast<const float4*>(entities + (size_t)(b * S + tail) * H)[t];

    float p[NR];
    const float* wc = w_rel + (size_t)(4 * t) * NR;
    const float* wh = w_rel + (size_t)(H + 4 * t) * NR;
    const float* wt = w_rel + (size_t)(2 * H + 4 * t) * NR;
    #pragma unroll
    for (int o = 0; o < NR; ++o)
        p[o] = c4.x * wc[o] + c4.y * wc[NR + o] + c4.z * wc[2 * NR + o] + c4.w * wc[3 * NR + o]
             + h4.x * wh[o] + h4.y * wh[NR + o] + h4.z * wh[2 * NR + o] + h4.w * wh[3 * NR + o]
             + t4.x * wt[o] + t4.y * wt[NR + o] + t4.z * wt[2 * NR + o] + t4.w * wt[3 * NR + o];

    if (t < E) {                        // wave 0: head size part
        const float sz = size_emb[(size_t)n_ent[b * S + head] * E + t];
        #pragma unroll
        for (int o = 0; o < NR; ++o) p[o] += sz * w_rel[(size_t)(3 * H + t) * NR + o];
    } else if (t >= 64 && t < 64 + E) { // wave 1: tail size part
        const int e = t - 64;
        const float sz = size_emb[(size_t)n_ent[b * S + tail] * E + e];
        #pragma unroll
        for (int o = 0; o < NR; ++o) p[o] += sz * w_rel[(size_t)(3 * H + E + e) * NR + o];
    }

    __shared__ float sred[3][NR];
    block_reduce_store<NR>(p, t, wave, lane, sred, b_rel,
                           rel_logits + (size_t)(b * R + r) * NR);
}

extern "C" void kernel_launch(void* const* d_in, const int* in_sizes, int n_in,
                              void* d_out, int out_size, void* d_ws, size_t ws_size,
                              hipStream_t stream) {
    const float* hidden    = (const float*)d_in[0];
    const int*   emask     = (const int*)  d_in[1];
    const int*   relations = (const int*)  d_in[2];
    const int*   cmask     = (const int*)  d_in[3];
    const float* size_emb  = (const float*)d_in[4];
    const float* w_span    = (const float*)d_in[5];
    const float* b_span    = (const float*)d_in[6];
    const float* w_rel     = (const float*)d_in[7];
    const float* b_rel     = (const float*)d_in[8];

    float* out        = (float*)d_out;
    float* ent_logits = out;                 // (B, S, NE) = 4000 floats
    float* rel_logits = out + B * S * NE;    // (B, R, NR) = 2400 floats

    float* ws       = (float*)d_ws;
    float* entities = ws;                                  // B*S*H floats
    float* rel_ctx  = entities + (size_t)B * S * H;        // B*R*H floats
    int*   n_ent    = (int*)(rel_ctx + (size_t)B * R * H); // B*S ints

    pool_kernel<<<B * (S + R), TPB, 0, stream>>>(
        hidden, emask, cmask, size_emb, w_span, b_span,
        entities, n_ent, rel_ctx, ent_logits);

    rel_kernel<<<B * R, TPB, 0, stream>>>(
        entities, n_ent, rel_ctx, relations, size_emb, w_rel, b_rel, rel_logits);
}